// Round 1
// baseline (326.939 us; speedup 1.0000x reference)
//
#include <hip/hip_runtime.h>

#define HIDDEN 1024
#define HEADS 16
#define HD 64
#define BATCH 2
#define SEQ 2048
#define MTOT (BATCH*SEQ)

typedef _Float16 f16;
typedef _Float16 half8 __attribute__((ext_vector_type(8)));
typedef _Float16 half4v __attribute__((ext_vector_type(4)));
typedef float floatx4 __attribute__((ext_vector_type(4)));

// ---------------- cast x (fp32 -> fp16) ----------------
__global__ __launch_bounds__(256) void cast_x_kernel(const float* __restrict__ x,
                                                     f16* __restrict__ xh) {
    int i = (blockIdx.x * 256 + threadIdx.x) * 4;
    floatx4 v = *(const floatx4*)(x + i);
    half4v o;
    #pragma unroll
    for (int j = 0; j < 4; ++j) o[j] = (f16)v[j];
    *(half4v*)(xh + i) = o;
}

// ------------- transpose-cast W [in][out] fp32 -> Wt [out][in] fp16 -------------
// grid (32,32,4), block (32,32). z selects which W.
__global__ void castT_kernel(const float* __restrict__ Wq, const float* __restrict__ Wk,
                             const float* __restrict__ Wv, const float* __restrict__ Wo,
                             f16* __restrict__ wt) {
    __shared__ float tile[32][33];
    int z = blockIdx.z;
    const float* W = (z == 0) ? Wq : (z == 1) ? Wk : (z == 2) ? Wv : Wo;
    int bx = blockIdx.x, by = blockIdx.y;
    int tx = threadIdx.x, ty = threadIdx.y;
    tile[ty][tx] = W[(by * 32 + ty) * HIDDEN + bx * 32 + tx];
    __syncthreads();
    // write Wt[out=bx*32+ty][in=by*32+tx]
    wt[(size_t)z * HIDDEN * HIDDEN + (bx * 32 + ty) * HIDDEN + by * 32 + tx] =
        (f16)tile[tx][ty];
}

// ---------------- fused QKV GEMM ----------------
// A = xh [4096 x 1024] row-major fp16, B = wt [3072 x 1024] (= concat Wq^T,Wk^T,Wv^T)
// C routed: proj0 -> q[bh][s][d], proj1 -> k[bh][s][d], proj2 -> vt[bh][d][s]
#define BM 128
#define BN 128
#define BK 32
#define APITCH 40  // fp16 elements; 80B rows, 16B-aligned

__global__ __launch_bounds__(256) void gemm_qkv(const f16* __restrict__ xh,
                                                const f16* __restrict__ wt,
                                                const float* __restrict__ bq,
                                                const float* __restrict__ bk,
                                                const float* __restrict__ bv,
                                                f16* __restrict__ qo, f16* __restrict__ ko,
                                                f16* __restrict__ vto) {
    __shared__ f16 As[BM * APITCH];
    __shared__ f16 Bs[BN * APITCH];
    const int m0 = blockIdx.y * BM;
    const int n0 = blockIdx.x * BN;
    const int t = threadIdx.x;
    const int lane = t & 63, w = t >> 6;
    const int wm = w >> 1, wn = w & 1;
    const int lr = lane & 15, quad = lane >> 4;

    floatx4 acc[4][4];
    #pragma unroll
    for (int i = 0; i < 4; ++i)
        #pragma unroll
        for (int j = 0; j < 4; ++j)
            #pragma unroll
            for (int r = 0; r < 4; ++r) acc[i][j][r] = 0.f;

    for (int k0 = 0; k0 < HIDDEN; k0 += BK) {
        #pragma unroll
        for (int it = 0; it < 2; ++it) {
            int s = t + it * 256;
            int row = s >> 2, kseg = s & 3;
            *(half8*)(&As[row * APITCH + kseg * 8]) =
                *(const half8*)(&xh[(size_t)(m0 + row) * HIDDEN + k0 + kseg * 8]);
            *(half8*)(&Bs[row * APITCH + kseg * 8]) =
                *(const half8*)(&wt[(size_t)(n0 + row) * HIDDEN + k0 + kseg * 8]);
        }
        __syncthreads();
        half8 af[4], bf[4];
        #pragma unroll
        for (int i = 0; i < 4; ++i)
            af[i] = *(half8*)(&As[(wm * 64 + i * 16 + lr) * APITCH + quad * 8]);
        #pragma unroll
        for (int j = 0; j < 4; ++j)
            bf[j] = *(half8*)(&Bs[(wn * 64 + j * 16 + lr) * APITCH + quad * 8]);
        #pragma unroll
        for (int i = 0; i < 4; ++i)
            #pragma unroll
            for (int j = 0; j < 4; ++j)
                acc[i][j] = __builtin_amdgcn_mfma_f32_16x16x32_f16(af[i], bf[j], acc[i][j], 0, 0, 0);
        __syncthreads();
    }

    // epilogue: route per-projection
    #pragma unroll
    for (int i = 0; i < 4; ++i) {
        int mbase = m0 + wm * 64 + i * 16 + quad * 4;
        #pragma unroll
        for (int j = 0; j < 4; ++j) {
            int n = n0 + wn * 64 + j * 16 + lr;
            int proj = n >> 10;           // 0=q 1=k 2=v (uniform per tile)
            int c = n & 1023;
            int h = c >> 6, d = c & 63;
            const float* bp = (proj == 0) ? bq : (proj == 1) ? bk : bv;
            float bias = bp[c];
            int m = mbase;
            int b = m >> 11, s = m & 2047;   // 4 consecutive rows stay in-batch
            int bh = b * HEADS + h;
            if (proj == 2) {
                half4v pv;
                #pragma unroll
                for (int r = 0; r < 4; ++r) pv[r] = (f16)(acc[i][j][r] + bias);
                *(half4v*)(&vto[((size_t)bh * HD + d) * SEQ + s]) = pv;
            } else {
                f16* dst = (proj == 0) ? qo : ko;
                #pragma unroll
                for (int r = 0; r < 4; ++r)
                    dst[((size_t)bh * SEQ + (s + r)) * HD + d] = (f16)(acc[i][j][r] + bias);
            }
        }
    }
}

// ---------------- flash attention ----------------
// grid: 512 blocks = (bh=32) x (qt=16), block 256 = 4 waves; wave owns 32 q-rows.
#define PPITCH 136

__global__ __launch_bounds__(256) void attn_kernel(const f16* __restrict__ q,
                                                   const f16* __restrict__ k,
                                                   const f16* __restrict__ vt,
                                                   f16* __restrict__ ctx) {
    __shared__ f16 Ps[128 * PPITCH];
    const int blk = blockIdx.x;
    const int qt = blk & 15, bh = blk >> 4;
    const int t = threadIdx.x;
    const int lane = t & 63, w = t >> 6;
    const int lr = lane & 15, quad = lane >> 4;

    const f16* qbh = q + (size_t)bh * SEQ * HD;
    const f16* kbh = k + (size_t)bh * SEQ * HD;
    const f16* vbh = vt + (size_t)bh * HD * SEQ;

    // Q fragments in registers: rows qt*128 + w*32 + mt*16 + lr, d = ks*32 + quad*8
    half8 qf[2][2];
    #pragma unroll
    for (int mt = 0; mt < 2; ++mt)
        #pragma unroll
        for (int ks = 0; ks < 2; ++ks)
            qf[mt][ks] = *(const half8*)(
                &qbh[(size_t)(qt * 128 + w * 32 + mt * 16 + lr) * HD + ks * 32 + quad * 8]);

    floatx4 oacc[2][4];
    float mrow[2][4], lrow[2][4];
    #pragma unroll
    for (int mt = 0; mt < 2; ++mt) {
        #pragma unroll
        for (int r = 0; r < 4; ++r) { mrow[mt][r] = -1e30f; lrow[mt][r] = 0.f; }
        #pragma unroll
        for (int nt4 = 0; nt4 < 4; ++nt4)
            #pragma unroll
            for (int r = 0; r < 4; ++r) oacc[mt][nt4][r] = 0.f;
    }

    for (int kt = 0; kt < 16; ++kt) {
        const f16* kbase = kbh + (size_t)kt * 128 * HD;
        floatx4 sacc[2][8];
        #pragma unroll
        for (int mt = 0; mt < 2; ++mt)
            #pragma unroll
            for (int nt = 0; nt < 8; ++nt)
                #pragma unroll
                for (int r = 0; r < 4; ++r) sacc[mt][nt][r] = 0.f;

        // QK^T: B operand straight from k (row-major [s][d] == Bt[n][k])
        #pragma unroll
        for (int nt = 0; nt < 8; ++nt) {
            half8 kf0 = *(const half8*)(&kbase[(size_t)(nt * 16 + lr) * HD + quad * 8]);
            half8 kf1 = *(const half8*)(&kbase[(size_t)(nt * 16 + lr) * HD + 32 + quad * 8]);
            sacc[0][nt] = __builtin_amdgcn_mfma_f32_16x16x32_f16(qf[0][0], kf0, sacc[0][nt], 0, 0, 0);
            sacc[0][nt] = __builtin_amdgcn_mfma_f32_16x16x32_f16(qf[0][1], kf1, sacc[0][nt], 0, 0, 0);
            sacc[1][nt] = __builtin_amdgcn_mfma_f32_16x16x32_f16(qf[1][0], kf0, sacc[1][nt], 0, 0, 0);
            sacc[1][nt] = __builtin_amdgcn_mfma_f32_16x16x32_f16(qf[1][1], kf1, sacc[1][nt], 0, 0, 0);
        }

        // online softmax per m-tile (rows quad*4+r owned by this 16-lane group)
        #pragma unroll
        for (int mt = 0; mt < 2; ++mt) {
            float mnew[4], alpha[4];
            #pragma unroll
            for (int r = 0; r < 4; ++r) {
                float mx = sacc[mt][0][r];
                #pragma unroll
                for (int nt = 1; nt < 8; ++nt) mx = fmaxf(mx, sacc[mt][nt][r]);
                mx *= 0.125f;  // 1/sqrt(64)
                mx = fmaxf(mx, __shfl_xor(mx, 1, 64));
                mx = fmaxf(mx, __shfl_xor(mx, 2, 64));
                mx = fmaxf(mx, __shfl_xor(mx, 4, 64));
                mx = fmaxf(mx, __shfl_xor(mx, 8, 64));
                float mo = mrow[mt][r];
                float mn = fmaxf(mo, mx);
                mnew[r] = mn;
                alpha[r] = exp2f((mo - mn) * 1.44269504f);
                mrow[mt][r] = mn;
            }
            float lsum[4] = {0.f, 0.f, 0.f, 0.f};
            #pragma unroll
            for (int nt = 0; nt < 8; ++nt) {
                #pragma unroll
                for (int r = 0; r < 4; ++r) {
                    float p = exp2f((sacc[mt][nt][r] * 0.125f - mnew[r]) * 1.44269504f);
                    lsum[r] += p;
                    Ps[(w * 32 + mt * 16 + quad * 4 + r) * PPITCH + nt * 16 + lr] = (f16)p;
                }
            }
            #pragma unroll
            for (int r = 0; r < 4; ++r) {
                float s = lsum[r];
                s += __shfl_xor(s, 1, 64);
                s += __shfl_xor(s, 2, 64);
                s += __shfl_xor(s, 4, 64);
                s += __shfl_xor(s, 8, 64);
                lrow[mt][r] = lrow[mt][r] * alpha[r] + s;
            }
            #pragma unroll
            for (int nt4 = 0; nt4 < 4; ++nt4)
                #pragma unroll
                for (int r = 0; r < 4; ++r) oacc[mt][nt4][r] *= alpha[r];
        }

        // PV: A = P from LDS (wave-private rows -> no barrier), B = vt [d][s]
        #pragma unroll
        for (int ks = 0; ks < 4; ++ks) {
            half8 pf0 = *(half8*)(&Ps[(w * 32 + 0 + lr) * PPITCH + ks * 32 + quad * 8]);
            half8 pf1 = *(half8*)(&Ps[(w * 32 + 16 + lr) * PPITCH + ks * 32 + quad * 8]);
            #pragma unroll
            for (int nt4 = 0; nt4 < 4; ++nt4) {
                half8 vf = *(const half8*)(
                    &vbh[(size_t)(nt4 * 16 + lr) * SEQ + kt * 128 + ks * 32 + quad * 8]);
                oacc[0][nt4] = __builtin_amdgcn_mfma_f32_16x16x32_f16(pf0, vf, oacc[0][nt4], 0, 0, 0);
                oacc[1][nt4] = __builtin_amdgcn_mfma_f32_16x16x32_f16(pf1, vf, oacc[1][nt4], 0, 0, 0);
            }
        }
    }

    // epilogue: normalize, write ctx in [b][s][h*64+d] fp16
    const int b = bh >> 4, h = bh & 15;
    #pragma unroll
    for (int mt = 0; mt < 2; ++mt) {
        #pragma unroll
        for (int r = 0; r < 4; ++r) {
            int row = qt * 128 + w * 32 + mt * 16 + quad * 4 + r;
            float inv = 1.f / lrow[mt][r];
            #pragma unroll
            for (int nt4 = 0; nt4 < 4; ++nt4)
                ctx[((size_t)(b * SEQ + row)) * HIDDEN + h * HD + nt4 * 16 + lr] =
                    (f16)(oacc[mt][nt4][r] * inv);
        }
    }
}

// ---------------- output projection GEMM (fp32 out + bias) ----------------
__global__ __launch_bounds__(256) void gemm_out(const f16* __restrict__ ah,
                                                const f16* __restrict__ wto,
                                                const float* __restrict__ bo,
                                                float* __restrict__ out) {
    __shared__ f16 As[BM * APITCH];
    __shared__ f16 Bs[BN * APITCH];
    const int m0 = blockIdx.y * BM;
    const int n0 = blockIdx.x * BN;
    const int t = threadIdx.x;
    const int lane = t & 63, w = t >> 6;
    const int wm = w >> 1, wn = w & 1;
    const int lr = lane & 15, quad = lane >> 4;

    floatx4 acc[4][4];
    #pragma unroll
    for (int i = 0; i < 4; ++i)
        #pragma unroll
        for (int j = 0; j < 4; ++j)
            #pragma unroll
            for (int r = 0; r < 4; ++r) acc[i][j][r] = 0.f;

    for (int k0 = 0; k0 < HIDDEN; k0 += BK) {
        #pragma unroll
        for (int it = 0; it < 2; ++it) {
            int s = t + it * 256;
            int row = s >> 2, kseg = s & 3;
            *(half8*)(&As[row * APITCH + kseg * 8]) =
                *(const half8*)(&ah[(size_t)(m0 + row) * HIDDEN + k0 + kseg * 8]);
            *(half8*)(&Bs[row * APITCH + kseg * 8]) =
                *(const half8*)(&wto[(size_t)(n0 + row) * HIDDEN + k0 + kseg * 8]);
        }
        __syncthreads();
        half8 af[4], bf[4];
        #pragma unroll
        for (int i = 0; i < 4; ++i)
            af[i] = *(half8*)(&As[(wm * 64 + i * 16 + lr) * APITCH + quad * 8]);
        #pragma unroll
        for (int j = 0; j < 4; ++j)
            bf[j] = *(half8*)(&Bs[(wn * 64 + j * 16 + lr) * APITCH + quad * 8]);
        #pragma unroll
        for (int i = 0; i < 4; ++i)
            #pragma unroll
            for (int j = 0; j < 4; ++j)
                acc[i][j] = __builtin_amdgcn_mfma_f32_16x16x32_f16(af[i], bf[j], acc[i][j], 0, 0, 0);
        __syncthreads();
    }

    #pragma unroll
    for (int i = 0; i < 4; ++i) {
        int mbase = m0 + wm * 64 + i * 16 + quad * 4;
        #pragma unroll
        for (int j = 0; j < 4; ++j) {
            int n = n0 + wn * 64 + j * 16 + lr;
            float bias = bo[n];
            #pragma unroll
            for (int r = 0; r < 4; ++r)
                out[(size_t)(mbase + r) * HIDDEN + n] = acc[i][j][r] + bias;
        }
    }
}

// ---------------- launch ----------------
extern "C" void kernel_launch(void* const* d_in, const int* in_sizes, int n_in,
                              void* d_out, int out_size, void* d_ws, size_t ws_size,
                              hipStream_t stream) {
    const float* x  = (const float*)d_in[0];
    const float* Wq = (const float*)d_in[1];
    const float* bq = (const float*)d_in[2];
    const float* Wk = (const float*)d_in[3];
    const float* bk = (const float*)d_in[4];
    const float* Wv = (const float*)d_in[5];
    const float* bv = (const float*)d_in[6];
    const float* Wo = (const float*)d_in[7];
    const float* bo = (const float*)d_in[8];
    float* out = (float*)d_out;

    char* ws = (char*)d_ws;
    f16* xh   = (f16*)(ws);                   // 8 MB: x fp16 [4096][1024]
    f16* wt   = (f16*)(ws + (8u  << 20));     // 8 MB: [Wq^T|Wk^T|Wv^T|Wo^T] fp16 [4][1024][1024]
    f16* qw   = (f16*)(ws + (16u << 20));     // 8 MB: q [32][2048][64]
    f16* kw   = (f16*)(ws + (24u << 20));     // 8 MB: k [32][2048][64]
    f16* vtw  = (f16*)(ws + (32u << 20));     // 8 MB: v^T [32][64][2048]
    f16* ctxh = (f16*)(ws + (40u << 20));     // 8 MB: ctx fp16 [4096][1024]

    cast_x_kernel<<<MTOT * HIDDEN / 1024, 256, 0, stream>>>(x, xh);
    castT_kernel<<<dim3(32, 32, 4), dim3(32, 32), 0, stream>>>(Wq, Wk, Wv, Wo, wt);
    gemm_qkv<<<dim3(3 * HIDDEN / BN, MTOT / BM), 256, 0, stream>>>(xh, wt, bq, bk, bv, qw, kw, vtw);
    attn_kernel<<<32 * (SEQ / 128), 256, 0, stream>>>(qw, kw, vtw, ctxh);
    gemm_out<<<dim3(HIDDEN / BN, MTOT / BM), 256, 0, stream>>>(ctxh, wt + (size_t)3 * HIDDEN * HIDDEN, bo, out);
}